// Round 1
// baseline (1015.944 us; speedup 1.0000x reference)
//
#include <hip/hip_runtime.h>
#include <math.h>

#define BB 4096
#define FF 50
#define DD 64
#define AA 64
#define PP 1225
#define PPAD 1280
#define NT 20     // tiles of 64 pairs
#define TPB 256

__global__ __launch_bounds__(TPB, 2)
void afm_kernel(const float* __restrict__ g_x,
                const float* __restrict__ g_W1,
                const float* __restrict__ g_b1,
                const float* __restrict__ g_w2,
                const float* __restrict__ g_p,
                float* __restrict__ g_out)
{
    __shared__ float xs[FF * DD];          // 12800 B
    __shared__ float w1s[DD * AA];         // 16384 B
    __shared__ float pt[64 * 66];          // prod tile, transposed [d][pair], stride 66
    __shared__ float elds[PPAD];           // logits, then exp values
    __shared__ unsigned short i0s[PPAD], i1s[PPAD];
    __shared__ float b1s[AA], w2s[AA];
    __shared__ float red[8];
    __shared__ float pool[4 * 64];

    const int tid = threadIdx.x;
    const int b = blockIdx.x;

    // ---- stage x[b] and W1 into LDS (coalesced float4) ----
    {
        const float4* gx4 = (const float4*)(g_x + (size_t)b * FF * DD);
        float4* xs4 = (float4*)xs;
        for (int i = tid; i < FF * DD / 4; i += TPB) xs4[i] = gx4[i];
        const float4* gw4 = (const float4*)g_W1;
        float4* w1s4 = (float4*)w1s;
        for (int i = tid; i < DD * AA / 4; i += TPB) w1s4[i] = gw4[i];
        if (tid < AA) { b1s[tid] = g_b1[tid]; w2s[tid] = g_w2[tid]; }
    }

    // ---- pair index tables (triu k=1, row-major) ----
    for (int p = tid; p < PPAD; p += TPB) {
        if (p < PP) {
            int i = 0, base = 0;
            while (base + (FF - 1 - i) <= p) { base += FF - 1 - i; ++i; }
            i0s[p] = (unsigned short)i;
            i1s[p] = (unsigned short)(p - base + i + 1);
        } else {
            i0s[p] = 0; i1s[p] = 0;
        }
    }
    __syncthreads();

    const int d  = tid & 63;   // phase-1 / phase-4 mapping
    const int pg = tid >> 6;
    const int ta = tid & 15;   // phase-2 mapping: lane-fast over a
    const int tp = tid >> 4;

    // ---- per-tile: prod -> (GEMM + ReLU + w2 dot) -> logits ----
    for (int t = 0; t < NT; ++t) {
        // phase 1: prod tile, transposed. lanes = d (conflict-free xs reads)
        #pragma unroll
        for (int k = 0; k < 16; ++k) {
            int pp = pg * 16 + k;
            int p = t * 64 + pp;
            float v = 0.f;
            if (p < PP) v = xs[i0s[p] * DD + d] * xs[i1s[p] * DD + d];
            pt[d * 66 + pp] = v;
        }
        __syncthreads();

        // phase 2: 64x64 tile, 4x4 per thread
        float acc[4][4] = {{0.f}};
        #pragma unroll 4
        for (int dd = 0; dd < 64; ++dd) {
            const float2* pv2 = (const float2*)&pt[dd * 66 + 4 * tp];
            float2 pa = pv2[0], pb = pv2[1];
            float pv[4] = {pa.x, pa.y, pb.x, pb.y};
            float4 wv = *(const float4*)&w1s[dd * 64 + 4 * ta];
            float wva[4] = {wv.x, wv.y, wv.z, wv.w};
            #pragma unroll
            for (int pi = 0; pi < 4; ++pi)
                #pragma unroll
                for (int ai = 0; ai < 4; ++ai)
                    acc[pi][ai] = fmaf(pv[pi], wva[ai], acc[pi][ai]);
        }
        // bias + relu + dot with w2 (h never materialized)
        float lp[4];
        #pragma unroll
        for (int pi = 0; pi < 4; ++pi) {
            float s = 0.f;
            #pragma unroll
            for (int ai = 0; ai < 4; ++ai) {
                float h = acc[pi][ai] + b1s[4 * ta + ai];
                h = fmaxf(h, 0.f);
                s = fmaf(h, w2s[4 * ta + ai], s);
            }
            lp[pi] = s;
        }
        // reduce over the 16 a-lanes (contiguous lanes share tp)
        #pragma unroll
        for (int off = 1; off < 16; off <<= 1)
            #pragma unroll
            for (int pi = 0; pi < 4; ++pi)
                lp[pi] += __shfl_xor(lp[pi], off, 64);
        if (ta == 0) {
            #pragma unroll
            for (int pi = 0; pi < 4; ++pi) {
                int p = t * 64 + 4 * tp + pi;
                if (p < PP) elds[p] = lp[pi];
            }
        }
        __syncthreads();
    }

    // ---- softmax over 1225 logits ----
    float m = -1e30f;
    for (int p = tid; p < PP; p += TPB) m = fmaxf(m, elds[p]);
    #pragma unroll
    for (int off = 32; off; off >>= 1) m = fmaxf(m, __shfl_xor(m, off, 64));
    if ((tid & 63) == 0) red[tid >> 6] = m;
    __syncthreads();
    m = fmaxf(fmaxf(red[0], red[1]), fmaxf(red[2], red[3]));

    float s = 0.f;
    for (int p = tid; p < PP; p += TPB) {
        float e = __expf(elds[p] - m);
        elds[p] = e;          // only this thread touched these slots
        s += e;
    }
    #pragma unroll
    for (int off = 32; off; off >>= 1) s += __shfl_xor(s, off, 64);
    if ((tid & 63) == 0) red[4 + (tid >> 6)] = s;
    __syncthreads();
    const float sumexp = red[4] + red[5] + red[6] + red[7];

    // ---- weighted pooling: pooled[d] = sum_p e[p]*prod[p][d] ----
    float accp = 0.f;
    for (int p = pg; p < PP; p += 4) {
        accp += elds[p] * xs[i0s[p] * DD + d] * xs[i1s[p] * DD + d];
    }
    pool[pg * 64 + d] = accp;
    __syncthreads();

    // ---- final projection ----
    if (tid < 64) {
        float tot = pool[tid] + pool[64 + tid] + pool[128 + tid] + pool[192 + tid];
        tot *= g_p[tid];
        #pragma unroll
        for (int off = 32; off; off >>= 1) tot += __shfl_xor(tot, off, 64);
        if (tid == 0) g_out[b] = tot / sumexp;
    }
}

extern "C" void kernel_launch(void* const* d_in, const int* in_sizes, int n_in,
                              void* d_out, int out_size, void* d_ws, size_t ws_size,
                              hipStream_t stream) {
    const float* g_x  = (const float*)d_in[0];
    const float* g_W1 = (const float*)d_in[1];
    const float* g_b1 = (const float*)d_in[2];
    const float* g_w2 = (const float*)d_in[3];
    const float* g_p  = (const float*)d_in[4];
    float* g_out = (float*)d_out;
    afm_kernel<<<BB, TPB, 0, stream>>>(g_x, g_W1, g_b1, g_w2, g_p, g_out);
}

// Round 2
// 481.101 us; speedup vs baseline: 2.1117x; 2.1117x over previous
//
#include <hip/hip_runtime.h>
#include <hip/hip_bf16.h>

typedef float f32x4 __attribute__((ext_vector_type(4)));
typedef short s16x8 __attribute__((ext_vector_type(8)));

#define BB 4096
#define FF 50
#define PP 1225
#define XS 68          // xs row stride (floats): 16B-aligned, spreads banks
#define NBLK 39        // ceil(1225/32) pair-blocks of 32
#define TPB 256

__global__ __launch_bounds__(TPB, 3)
void afm_mfma(const float* __restrict__ g_x, const float* __restrict__ g_W1,
              const float* __restrict__ g_b1, const float* __restrict__ g_w2,
              const float* __restrict__ g_p, float* __restrict__ g_out)
{
    __shared__ __align__(16) float xs[FF * XS];          // 13.6 KB
    __shared__ __align__(16) short wpkh[512 * 8];        // 8 KB  W1 hi frags, frag-ordered
    __shared__ __align__(16) short wpkl[512 * 8];        // 8 KB  W1 lo frags
    __shared__ unsigned short i0s[1248], i1s[1248];      // 5 KB
    __shared__ __align__(16) float b1s[64], w2s[64];
    __shared__ float poolw[4][64];
    __shared__ float mw_s[4], sw_s[4];

    const int tid = threadIdx.x;
    const int b = blockIdx.x;

    // ---- stage x[b] into LDS at stride XS ----
    {
        const float4* gx4 = (const float4*)(g_x + (size_t)b * FF * 64);
        for (int i = tid; i < FF * 16; i += TPB) {
            float4 v = gx4[i];
            int row = i >> 4, col = (i & 15) << 2;
            *(float4*)&xs[row * XS + col] = v;
        }
    }
    if (tid < 64) { b1s[tid] = g_b1[tid]; w2s[tid] = g_w2[tid]; }

    // ---- pack W1 into MFMA A-fragment order, split bf16 hi/lo ----
    // entry e = (t, ma, lane): A[a=ma*16+(lane&15)][k=32t+(lane>>4)*8+j] = W1[k][a]
    for (int e = tid; e < 512; e += TPB) {
        int t = e >> 8, rem = e & 255, ma = rem >> 6, ln = rem & 63;
        int gg = ln >> 4, col = ma * 16 + (ln & 15);
        s16x8 h, l;
        #pragma unroll
        for (int j = 0; j < 8; ++j) {
            float v = g_W1[(t * 32 + gg * 8 + j) * 64 + col];
            __hip_bfloat16 hb = __float2bfloat16(v);
            float hf = __bfloat162float(hb);
            __hip_bfloat16 lb = __float2bfloat16(v - hf);
            h[j] = (short)__bfloat16_as_ushort(hb);
            l[j] = (short)__bfloat16_as_ushort(lb);
        }
        *(s16x8*)&wpkh[e * 8] = h;
        *(s16x8*)&wpkl[e * 8] = l;
    }

    // ---- pair index tables (triu k=1), padded to 1248 ----
    for (int p = tid; p < 1248; p += TPB) {
        unsigned short a = 0, c = 0;
        if (p < PP) {
            int i = 0, base = 0;
            while (base + (FF - 1 - i) <= p) { base += FF - 1 - i; ++i; }
            a = (unsigned short)i;
            c = (unsigned short)(p - base + i + 1);
        }
        i0s[p] = a; i1s[p] = c;
    }
    __syncthreads();

    const int lane = tid & 63, wq = tid >> 6, g = lane >> 4, pl = lane & 15;

    float m_w = -1e30f, s_w = 0.f;
    float acc8[2][8];
    #pragma unroll
    for (int t = 0; t < 2; ++t)
        #pragma unroll
        for (int j = 0; j < 8; ++j) acc8[t][j] = 0.f;

    // ---- main loop: per-wave independent 32-pair blocks, no barriers ----
    for (int blk = wq; blk < NBLK; blk += 4) {
        const int base = blk * 32;
        f32x4 acc[2][4];
        #pragma unroll
        for (int nt = 0; nt < 2; ++nt)
            #pragma unroll
            for (int ma = 0; ma < 4; ++ma) {
                f32x4 z = {0.f, 0.f, 0.f, 0.f};
                acc[nt][ma] = z;
            }

        float prodf[2][2][8];
        int ia[2], ib[2];
        #pragma unroll
        for (int nt = 0; nt < 2; ++nt) {
            int p = base + nt * 16 + pl;
            ia[nt] = i0s[p]; ib[nt] = i1s[p];
        }

        #pragma unroll
        for (int t = 0; t < 2; ++t) {
            s16x8 pfh[2], pfl[2];
            #pragma unroll
            for (int nt = 0; nt < 2; ++nt) {
                const float* x0 = &xs[ia[nt] * XS + t * 32 + g * 8];
                const float* x1 = &xs[ib[nt] * XS + t * 32 + g * 8];
                f32x4 a0 = *(const f32x4*)x0, a1 = *(const f32x4*)(x0 + 4);
                f32x4 c0 = *(const f32x4*)x1, c1 = *(const f32x4*)(x1 + 4);
                s16x8 ph, plv;
                #pragma unroll
                for (int j = 0; j < 4; ++j) {
                    float pr = a0[j] * c0[j];
                    prodf[nt][t][j] = pr;
                    __hip_bfloat16 hb = __float2bfloat16(pr);
                    ph[j] = (short)__bfloat16_as_ushort(hb);
                    plv[j] = (short)__bfloat16_as_ushort(
                        __float2bfloat16(pr - __bfloat162float(hb)));
                }
                #pragma unroll
                for (int j = 0; j < 4; ++j) {
                    float pr = a1[j] * c1[j];
                    prodf[nt][t][4 + j] = pr;
                    __hip_bfloat16 hb = __float2bfloat16(pr);
                    ph[4 + j] = (short)__bfloat16_as_ushort(hb);
                    plv[4 + j] = (short)__bfloat16_as_ushort(
                        __float2bfloat16(pr - __bfloat162float(hb)));
                }
                pfh[nt] = ph; pfl[nt] = plv;
            }
            #pragma unroll
            for (int ma = 0; ma < 4; ++ma) {
                const s16x8 wh = *(const s16x8*)&wpkh[((t * 4 + ma) * 64 + lane) * 8];
                const s16x8 wl = *(const s16x8*)&wpkl[((t * 4 + ma) * 64 + lane) * 8];
                #pragma unroll
                for (int nt = 0; nt < 2; ++nt) {
                    acc[nt][ma] = __builtin_amdgcn_mfma_f32_16x16x32_bf16(wh, pfh[nt], acc[nt][ma], 0, 0, 0);
                    acc[nt][ma] = __builtin_amdgcn_mfma_f32_16x16x32_bf16(wl, pfh[nt], acc[nt][ma], 0, 0, 0);
                    acc[nt][ma] = __builtin_amdgcn_mfma_f32_16x16x32_bf16(wh, pfl[nt], acc[nt][ma], 0, 0, 0);
                }
            }
        }

        // ---- logits: bias + ReLU + w2 dot, reduce over a (rows) ----
        float lg0 = 0.f, lg1 = 0.f;
        #pragma unroll
        for (int ma = 0; ma < 4; ++ma) {
            f32x4 bv = *(const f32x4*)&b1s[ma * 16 + g * 4];
            f32x4 wv = *(const f32x4*)&w2s[ma * 16 + g * 4];
            #pragma unroll
            for (int r = 0; r < 4; ++r) {
                lg0 = fmaf(fmaxf(acc[0][ma][r] + bv[r], 0.f), wv[r], lg0);
                lg1 = fmaf(fmaxf(acc[1][ma][r] + bv[r], 0.f), wv[r], lg1);
            }
        }
        lg0 += __shfl_xor(lg0, 16); lg0 += __shfl_xor(lg0, 32);
        lg1 += __shfl_xor(lg1, 16); lg1 += __shfl_xor(lg1, 32);
        if (base + pl >= PP)      lg0 = -1e30f;
        if (base + 16 + pl >= PP) lg1 = -1e30f;

        // ---- per-wave online softmax + in-register pooling ----
        float tmax = fmaxf(lg0, lg1);
        tmax = fmaxf(tmax, __shfl_xor(tmax, 1));
        tmax = fmaxf(tmax, __shfl_xor(tmax, 2));
        tmax = fmaxf(tmax, __shfl_xor(tmax, 4));
        tmax = fmaxf(tmax, __shfl_xor(tmax, 8));
        float mnew = fmaxf(m_w, tmax);
        float fac = __expf(m_w - mnew);
        m_w = mnew;
        float e0 = __expf(lg0 - m_w), e1 = __expf(lg1 - m_w);
        s_w = fmaf(s_w, fac, e0 + e1);
        #pragma unroll
        for (int t = 0; t < 2; ++t)
            #pragma unroll
            for (int j = 0; j < 8; ++j)
                acc8[t][j] = fmaf(e0, prodf[0][t][j],
                              fmaf(e1, prodf[1][t][j], acc8[t][j] * fac));
    }

    // ---- wave finalize: reduce over pair-lanes ----
    s_w += __shfl_xor(s_w, 1); s_w += __shfl_xor(s_w, 2);
    s_w += __shfl_xor(s_w, 4); s_w += __shfl_xor(s_w, 8);
    #pragma unroll
    for (int t = 0; t < 2; ++t)
        #pragma unroll
        for (int j = 0; j < 8; ++j) {
            float v = acc8[t][j];
            v += __shfl_xor(v, 1); v += __shfl_xor(v, 2);
            v += __shfl_xor(v, 4); v += __shfl_xor(v, 8);
            acc8[t][j] = v;
        }
    if (pl == 0) {
        #pragma unroll
        for (int t = 0; t < 2; ++t)
            #pragma unroll
            for (int j = 0; j < 8; ++j)
                poolw[wq][t * 32 + g * 8 + j] = acc8[t][j];
    }
    if (lane == 0) { mw_s[wq] = m_w; sw_s[wq] = s_w; }
    __syncthreads();

    // ---- merge 4 waves + projection ----
    if (tid < 64) {
        float mg = fmaxf(fmaxf(mw_s[0], mw_s[1]), fmaxf(mw_s[2], mw_s[3]));
        float f0 = __expf(mw_s[0] - mg), f1 = __expf(mw_s[1] - mg);
        float f2 = __expf(mw_s[2] - mg), f3 = __expf(mw_s[3] - mg);
        float sg = f0 * sw_s[0] + f1 * sw_s[1] + f2 * sw_s[2] + f3 * sw_s[3];
        float pd = f0 * poolw[0][tid] + f1 * poolw[1][tid]
                 + f2 * poolw[2][tid] + f3 * poolw[3][tid];
        float v = pd * g_p[tid];
        v += __shfl_xor(v, 1);  v += __shfl_xor(v, 2);  v += __shfl_xor(v, 4);
        v += __shfl_xor(v, 8);  v += __shfl_xor(v, 16); v += __shfl_xor(v, 32);
        if (tid == 0) g_out[b] = v / sg;
    }
}

extern "C" void kernel_launch(void* const* d_in, const int* in_sizes, int n_in,
                              void* d_out, int out_size, void* d_ws, size_t ws_size,
                              hipStream_t stream) {
    const float* g_x  = (const float*)d_in[0];
    const float* g_W1 = (const float*)d_in[1];
    const float* g_b1 = (const float*)d_in[2];
    const float* g_w2 = (const float*)d_in[3];
    const float* g_p  = (const float*)d_in[4];
    float* g_out = (float*)d_out;
    afm_mfma<<<BB, TPB, 0, stream>>>(g_x, g_W1, g_b1, g_w2, g_p, g_out);
}